// Round 1
// baseline (396.054 us; speedup 1.0000x reference)
//
#include <hip/hip_runtime.h>
#include <hip/hip_bf16.h>

#define NSEQ 2048
#define DM 512
#define BATCH 8
#define GTOT (BATCH * NSEQ)          // 16384
#define INV_T 0.044194173824159216f  // 1/sqrt(512)
#define EPSN 1e-5f

typedef __bf16 bf16_t;
typedef bf16_t bf16x8 __attribute__((ext_vector_type(8)));
typedef float f32x16 __attribute__((ext_vector_type(16)));
typedef unsigned short u16;
typedef unsigned int u32;
typedef unsigned char u8;
typedef unsigned long long u64;

__device__ __forceinline__ u16 f2bf(float f) {
    u32 u = __builtin_bit_cast(u32, f);
    u32 r = (u + 0x7FFFu + ((u >> 16) & 1u)) >> 16;
    return (u16)r;
}

// async global->LDS DMA, 16 B per lane. LDS dest = wave-uniform base + lane*16 B.
__device__ __forceinline__ void async16(const u16* g, u16* l) {
    __builtin_amdgcn_global_load_lds(
        (const __attribute__((address_space(1))) u32*)g,
        (__attribute__((address_space(3))) u32*)l, 16, 0, 0);
}

// BK=64 LDS tile: rows x 64 k-elems (128 B rows), 8 16-B chunks XOR-swizzled by ((row>>1)&7).
__device__ __forceinline__ bf16x8 fragld64(const u16* t, int row, int kc) {
    return *(const bf16x8*)(t + row * 64 + ((kc ^ ((row >> 1) & 7)) << 3));
}

#define MFMA32(a, b, c) __builtin_amdgcn_mfma_f32_32x32x16_bf16(a, b, c, 0, 0, 0)
#define ROWOFF(reg, lh) (((reg) & 3) + 8 * ((reg) >> 2) + 4 * (lh))

// BK=64 staging: 8 issues/thread (4 A + 4 B). Issue u = wave*4+j covers LDS rows
// u*8..u*8+7; lane supplies row u*8+(lane>>3), chunk (lane&7), fetching the
// global chunk that fragld64's XOR expects at that slot.
#define STAGE64(Ag, ldA, Bg, ldB, k0)                                            \
    do {                                                                         \
        _Pragma("unroll") for (int j = 0; j < 4; ++j) {                          \
            const int cg = (lane & 7) ^ ((j * 4 + (lane >> 4)) & 7);             \
            const int dst = (wave * 4 + j) * 512 + lane * 8;                     \
            async16((Ag) + (long)(rS + j * 8) * (ldA) + (k0) + cg * 8, Ab + dst);\
            async16((Bg) + (long)(rS + j * 8) * (ldB) + (k0) + cg * 8, Bb + dst);\
        }                                                                        \
    } while (0)

// ---------------- kernel 1: f32 -> bf16 of X and W ----------------
__global__ __launch_bounds__(256) void k_convert(
    const float* __restrict__ X, const float* __restrict__ W,
    u16* __restrict__ Kbf, u16* __restrict__ Wbf) {
    const long NK = (long)GTOT * DM / 4;  // 2097152
    const long NW = (long)DM * DM / 4;    // 65536
    long i = (long)blockIdx.x * 256 + threadIdx.x;
    if (i < NK) {
        float4 f = ((const float4*)X)[i];
        ushort4 o;
        o.x = f2bf(f.x); o.y = f2bf(f.y); o.z = f2bf(f.z); o.w = f2bf(f.w);
        ((ushort4*)Kbf)[i] = o;
    } else if (i < NK + NW) {
        long j = i - NK;
        float4 f = ((const float4*)W)[j];
        ushort4 o;
        o.x = f2bf(f.x); o.y = f2bf(f.y); o.z = f2bf(f.z); o.w = f2bf(f.w);
        ((ushort4*)Wbf)[j] = o;
    }
}

// ------------- kernel 1b: bit-pack mask, float4 loads + LDS nibble assembly -------------
__global__ __launch_bounds__(256) void k_maskpack(
    const float* __restrict__ mask, u64* __restrict__ Mbits) {
    __shared__ u8 nib[256];
    const int tid = threadIdx.x;
    const long fbase = (long)blockIdx.x * 256 + tid;  // float4 index
    float4 f = ((const float4*)mask)[fbase];
    unsigned n = (f.x != 0.f ? 1u : 0u) | (f.y != 0.f ? 2u : 0u) |
                 (f.z != 0.f ? 4u : 0u) | (f.w != 0.f ? 8u : 0u);
    nib[tid] = (u8)n;
    __syncthreads();
    if (tid < 16) {
        u64 w = 0;
#pragma unroll
        for (int i = 0; i < 16; ++i) w |= (u64)nib[tid * 16 + i] << (i * 4);
        Mbits[(long)blockIdx.x * 16 + tid] = w;
    }
}

// ------------- kernel 3: vT[e][g] = elu(W X^T + b), 128x128 BK=64 -------------
__global__ __launch_bounds__(256, 4) void k_vgemm(
    const u16* __restrict__ Wbf, const u16* __restrict__ Kbf,
    const float* __restrict__ bias, u16* __restrict__ vT) {
    __shared__ __attribute__((aligned(16))) u16 Ab[8192], Bb[8192];
    const int tid = threadIdx.x, wave = tid >> 6, lane = tid & 63;
    const int l31 = lane & 31, lh = lane >> 5;
    const int wy = wave >> 1, wx = wave & 1;
    const int M0 = blockIdx.y * 128, N0 = blockIdx.x * 128;
    const u16* Ag = Wbf + (long)M0 * DM;
    const u16* Bg = Kbf + (long)N0 * DM;

    const int rS = wave * 32 + (lane >> 3);

    f32x16 acc[2][2];
#pragma unroll
    for (int i = 0; i < 2; ++i)
#pragma unroll
        for (int j = 0; j < 2; ++j)
#pragma unroll
            for (int e = 0; e < 16; ++e) acc[i][j][e] = 0.f;

    for (int kt = 0; kt < 8; ++kt) {
        const int k0 = kt * 64;
        __syncthreads();
        STAGE64(Ag, DM, Bg, DM, k0);
        __syncthreads();
#pragma unroll
        for (int ks = 0; ks < 4; ++ks) {
            const int kc = ks * 2 + lh;
            bf16x8 a0 = fragld64(Ab, wy * 64 + l31, kc);
            bf16x8 a1 = fragld64(Ab, wy * 64 + 32 + l31, kc);
            bf16x8 b0 = fragld64(Bb, wx * 64 + l31, kc);
            bf16x8 b1 = fragld64(Bb, wx * 64 + 32 + l31, kc);
            acc[0][0] = MFMA32(a0, b0, acc[0][0]);
            acc[0][1] = MFMA32(a0, b1, acc[0][1]);
            acc[1][0] = MFMA32(a1, b0, acc[1][0]);
            acc[1][1] = MFMA32(a1, b1, acc[1][1]);
        }
    }
#pragma unroll
    for (int mi = 0; mi < 2; ++mi) {
#pragma unroll
        for (int reg = 0; reg < 16; ++reg) {
            int e = M0 + wy * 64 + mi * 32 + ROWOFF(reg, lh);
            float bv = bias[e];
#pragma unroll
            for (int ni = 0; ni < 2; ++ni) {
                int g = N0 + wx * 64 + ni * 32 + l31;
                float x = acc[mi][ni][reg] + bv;
                float v = x > 0.f ? x : (__expf(x) - 1.f);
                vT[(long)e * GTOT + g] = f2bf(v);
            }
        }
    }
}

// -------- kernel 4 (FUSED): per 64-row Q-tile, flash-style over kv:
//   S = bitmask .* (Q K^T) * INV_T  (f32 acc -> bf16 via LDS),
//   O += S V   (V frags direct from L2-resident vT),
//   ss += S^2 row-wise;   end: O *= 1/max(sqrt(ss), eps).
// 512 thr / 8 waves. batch = blockIdx.x & 7 -> XCD affinity (K+V = 4 MiB = 1 L2).
// Wave w: QK columns kv0+32w..+31 (both 32-row halves); PV d-cols 64w..64w+63.
__global__ __launch_bounds__(512, 2) void k_fused(
    const u16* __restrict__ Kbf, const u16* __restrict__ vT,
    const u32* __restrict__ Mw, float* __restrict__ Out) {
    // Qb: 64 rows x 512 k, 16-B chunks stored at slot (c ^ (row&31)) -> conflict-free frag reads
    __shared__ __attribute__((aligned(16))) u16 Qb[64 * 512];
    // Sb: 64 rows x 256 kv, same XOR swizzle (32 chunks/row)
    __shared__ __attribute__((aligned(16))) u16 Sb[64 * 256];
    __shared__ float ssred[8][64];
    __shared__ float ssinv[64];

    const int tid = threadIdx.x;
    const int w = tid >> 6, lane = tid & 63, l31 = lane & 31, lh = lane >> 5;
    const int b = blockIdx.x & 7, q = blockIdx.x >> 3;
    const int M0 = q * 64;
    const long rowbase = (long)b * NSEQ + M0;

    // ---- stage Q tile (swizzled source, linear LDS dest) ----
    {
        const u16* src = Kbf + rowbase * DM;
#pragma unroll
        for (int it = 0; it < 8; ++it) {
            int idx = it * 512 + tid;  // 16-B chunk index, 0..4095
            int row = idx >> 6, cd = idx & 63;
            int cg = cd ^ (row & 31);
            async16(src + (long)row * DM + cg * 8, Qb + idx * 8);
        }
    }

    f32x16 oc[2][2];
#pragma unroll
    for (int i = 0; i < 2; ++i)
#pragma unroll
        for (int j = 0; j < 2; ++j)
#pragma unroll
            for (int e = 0; e < 16; ++e) oc[i][j][e] = 0.f;

    float ss[32];
#pragma unroll
    for (int i = 0; i < 32; ++i) ss[i] = 0.f;

    // per-lane operand pointers
    const u16* kp = Kbf + ((long)b * NSEQ + 32 * w + l31) * DM + lh * 8;
    const u16* vp0 = vT + (long)(64 * w + l31) * GTOT + (long)b * NSEQ + lh * 8;
    const u16* vp1 = vp0 + (long)32 * GTOT;
    const u32* Mb = Mw + rowbase * 64;  // 64 u32 words per row

    __syncthreads();  // Q staged (compiler drains vmcnt before barrier)

#pragma unroll 1
    for (int t = 0; t < 8; ++t) {
        const int kv0 = t * 256;
        // ---- QK^T: wave w owns kv cols 32w..32w+31, rows 0..63 (two halves) ----
        f32x16 p0, p1;
#pragma unroll
        for (int e = 0; e < 16; ++e) { p0[e] = 0.f; p1[e] = 0.f; }
        const u16* kpt = kp + (long)kv0 * DM;
#pragma unroll
        for (int ks = 0; ks < 32; ++ks) {
            bf16x8 bk = *(const bf16x8*)(kpt + ks * 16);
            const int sl = ((2 * ks + lh) ^ l31) << 3;
            bf16x8 a0 = *(const bf16x8*)(Qb + l31 * DM + sl);
            bf16x8 a1 = *(const bf16x8*)(Qb + (32 + l31) * DM + sl);
            p0 = MFMA32(a0, bk, p0);
            p1 = MFMA32(a1, bk, p1);
        }
        __syncthreads();  // all waves done reading Sb from previous PV
        // ---- mask + INV_T + sum-of-squares + bf16 -> Sb ----
        const int col = 32 * w + l31;
        const u32* mb = Mb + t * 8 + w;  // word index (col>>5) = t*8+w, uniform per lane-half
#pragma unroll
        for (int sr = 0; sr < 2; ++sr) {
#pragma unroll
            for (int reg = 0; reg < 16; ++reg) {
                const int row = 32 * sr + ROWOFF(reg, lh);
                u32 mwd = mb[row * 64];
                float s = ((mwd >> l31) & 1u) ? (sr ? p1[reg] : p0[reg]) * INV_T : 0.f;
                ss[sr * 16 + reg] += s * s;
                int cw = (col >> 3) ^ (row & 31);
                Sb[row * 256 + cw * 8 + (col & 7)] = f2bf(s);
            }
        }
        __syncthreads();  // Sb ready
        // ---- PV: all waves rows 0..63; wave w owns d cols 64w..64w+63 ----
#pragma unroll
        for (int ks = 0; ks < 16; ++ks) {
            const int sl = ((2 * ks + lh) ^ l31) << 3;
            bf16x8 a0 = *(const bf16x8*)(Sb + l31 * 256 + sl);
            bf16x8 a1 = *(const bf16x8*)(Sb + (32 + l31) * 256 + sl);
            bf16x8 v0 = *(const bf16x8*)(vp0 + kv0 + ks * 16);
            bf16x8 v1 = *(const bf16x8*)(vp1 + kv0 + ks * 16);
            oc[0][0] = MFMA32(a0, v0, oc[0][0]);
            oc[0][1] = MFMA32(a0, v1, oc[0][1]);
            oc[1][0] = MFMA32(a1, v0, oc[1][0]);
            oc[1][1] = MFMA32(a1, v1, oc[1][1]);
        }
    }

    // ---- row norms: reduce ss over the 32 col-lanes, then over the 8 waves ----
#pragma unroll
    for (int i = 0; i < 32; ++i) {
        float v = ss[i];
        v += __shfl_xor(v, 1, 32);
        v += __shfl_xor(v, 2, 32);
        v += __shfl_xor(v, 4, 32);
        v += __shfl_xor(v, 8, 32);
        v += __shfl_xor(v, 16, 32);
        ss[i] = v;
    }
    if (l31 == 0) {
#pragma unroll
        for (int sr = 0; sr < 2; ++sr)
#pragma unroll
            for (int reg = 0; reg < 16; ++reg)
                ssred[w][32 * sr + ROWOFF(reg, lh)] = ss[sr * 16 + reg];
    }
    __syncthreads();
    if (tid < 64) {
        float v = 0.f;
#pragma unroll
        for (int j = 0; j < 8; ++j) v += ssred[j][tid];
        ssinv[tid] = 1.f / fmaxf(sqrtf(v), EPSN);
    }
    __syncthreads();

    // ---- scaled output, nontemporal (don't thrash L2-resident K/V) ----
    float* ob = Out + rowbase * DM;
#pragma unroll
    for (int ms = 0; ms < 2; ++ms) {
#pragma unroll
        for (int reg = 0; reg < 16; ++reg) {
            const int row = 32 * ms + ROWOFF(reg, lh);
            const float scl = ssinv[row];
            float* op = ob + (long)row * DM + 64 * w + l31;
            __builtin_nontemporal_store(oc[ms][0][reg] * scl, op);
            __builtin_nontemporal_store(oc[ms][1][reg] * scl, op + 32);
        }
    }
}

extern "C" void kernel_launch(void* const* d_in, const int* in_sizes, int n_in,
                              void* d_out, int out_size, void* d_ws, size_t ws_size,
                              hipStream_t stream) {
    const float* X = (const float*)d_in[0];
    const float* mask = (const float*)d_in[1];
    const float* W = (const float*)d_in[2];
    const float* bias = (const float*)d_in[3];
    float* out = (float*)d_out;

    char* ws = (char*)d_ws;
    u16* Kbf = (u16*)ws;                      // 16 MiB
    u16* Wbf = (u16*)(ws + 16777216);         // 512 KiB
    u16* vT = (u16*)(ws + 17301504);          // 16 MiB
    u64* Mbits = (u64*)(ws + 101253120);      // 4 MiB (packed mask)

    k_convert<<<8448, 256, 0, stream>>>(X, W, Kbf, Wbf);
    k_maskpack<<<32768, 256, 0, stream>>>(mask, Mbits);
    k_vgemm<<<dim3(128, 4), 256, 0, stream>>>(Wbf, Kbf, bias, vT);
    k_fused<<<256, 512, 0, stream>>>(Kbf, vT, (const u32*)Mbits, out);
}

// Round 2
// 391.229 us; speedup vs baseline: 1.0123x; 1.0123x over previous
//
#include <hip/hip_runtime.h>
#include <hip/hip_bf16.h>

#define NSEQ 2048
#define DM 512
#define BATCH 8
#define GTOT (BATCH * NSEQ)          // 16384
#define INV_T 0.044194173824159216f  // 1/sqrt(512)
#define EPSN 1e-5f

typedef __bf16 bf16_t;
typedef bf16_t bf16x8 __attribute__((ext_vector_type(8)));
typedef float f32x16 __attribute__((ext_vector_type(16)));
typedef unsigned short u16;
typedef unsigned int u32;
typedef unsigned char u8;
typedef unsigned long long u64;

__device__ __forceinline__ u16 f2bf(float f) {
    u32 u = __builtin_bit_cast(u32, f);
    u32 r = (u + 0x7FFFu + ((u >> 16) & 1u)) >> 16;
    return (u16)r;
}

// async global->LDS DMA, 16 B per lane. LDS dest = wave-uniform base + lane*16 B.
__device__ __forceinline__ void async16(const u16* g, u16* l) {
    __builtin_amdgcn_global_load_lds(
        (const __attribute__((address_space(1))) u32*)g,
        (__attribute__((address_space(3))) u32*)l, 16, 0, 0);
}

// BK=64 LDS tile: rows x 64 k-elems (128 B rows), 8 16-B chunks XOR-swizzled by ((row>>1)&7).
__device__ __forceinline__ bf16x8 fragld64(const u16* t, int row, int kc) {
    return *(const bf16x8*)(t + row * 64 + ((kc ^ ((row >> 1) & 7)) << 3));
}

#define MFMA32(a, b, c) __builtin_amdgcn_mfma_f32_32x32x16_bf16(a, b, c, 0, 0, 0)
#define ROWOFF(reg, lh) (((reg) & 3) + 8 * ((reg) >> 2) + 4 * (lh))

// raw barrier / counted waits (no compiler vmcnt(0) drain)
#define BAR() asm volatile("s_barrier" ::: "memory")
#define VMCNT(n) asm volatile("s_waitcnt vmcnt(" #n ")" ::: "memory")

// BK=64 staging for 4-wave/128-row kernels (k_vgemm, k_pv).
#define STAGE64(Ag, ldA, Bg, ldB, k0)                                            \
    do {                                                                         \
        _Pragma("unroll") for (int j = 0; j < 4; ++j) {                          \
            const int cg = (lane & 7) ^ ((j * 4 + (lane >> 4)) & 7);             \
            const int dst = (wave * 4 + j) * 512 + lane * 8;                     \
            async16((Ag) + (long)(rS + j * 8) * (ldA) + (k0) + cg * 8, Ab + dst);\
            async16((Bg) + (long)(rS + j * 8) * (ldB) + (k0) + cg * 8, Bb + dst);\
        }                                                                        \
    } while (0)

// one-operand staging for the 8-wave/256-row kernel: 4 issues/thread -> 256 rows x 64 k.
// wave*16 mod 8 == 0, so the XOR source formula is identical to STAGE64's.
#define STG(g, ld, k0, dst)                                                      \
    do {                                                                         \
        _Pragma("unroll") for (int j = 0; j < 4; ++j) {                          \
            const int cg = (lane & 7) ^ ((j * 4 + (lane >> 4)) & 7);             \
            async16((g) + (long)(rS + j * 8) * (ld) + (k0) + cg * 8,             \
                    (dst) + (wave * 4 + j) * 512 + lane * 8);                    \
        }                                                                        \
    } while (0)

// half-K-tile MFMA phase for the 256x256 kernel: 2 k-slices x (4x2) tiles = 16 MFMA.
#define QPHASE(Ac, Bc, ks0)                                                      \
    do {                                                                         \
        _Pragma("unroll") for (int ks = (ks0); ks < (ks0) + 2; ++ks) {           \
            const int kc = ks * 2 + lh;                                          \
            bf16x8 b0 = fragld64((Bc), wx * 64 + l31, kc);                       \
            bf16x8 b1 = fragld64((Bc), wx * 64 + 32 + l31, kc);                  \
            bf16x8 a0 = fragld64((Ac), wy * 128 + l31, kc);                      \
            bf16x8 a1 = fragld64((Ac), wy * 128 + 32 + l31, kc);                 \
            bf16x8 a2 = fragld64((Ac), wy * 128 + 64 + l31, kc);                 \
            bf16x8 a3 = fragld64((Ac), wy * 128 + 96 + l31, kc);                 \
            __builtin_amdgcn_s_setprio(1);                                       \
            acc[0][0] = MFMA32(a0, b0, acc[0][0]);                               \
            acc[0][1] = MFMA32(a0, b1, acc[0][1]);                               \
            acc[1][0] = MFMA32(a1, b0, acc[1][0]);                               \
            acc[1][1] = MFMA32(a1, b1, acc[1][1]);                               \
            acc[2][0] = MFMA32(a2, b0, acc[2][0]);                               \
            acc[2][1] = MFMA32(a2, b1, acc[2][1]);                               \
            acc[3][0] = MFMA32(a3, b0, acc[3][0]);                               \
            acc[3][1] = MFMA32(a3, b1, acc[3][1]);                               \
            __builtin_amdgcn_s_setprio(0);                                       \
        }                                                                        \
    } while (0)

// ---------------- kernel 1: f32 -> bf16 of X and W; zero ssbuf ----------------
__global__ __launch_bounds__(256) void k_convert(
    const float* __restrict__ X, const float* __restrict__ W,
    u16* __restrict__ Kbf, u16* __restrict__ Wbf, float* __restrict__ ssbuf) {
    const long NK = (long)GTOT * DM / 4;  // 2097152
    const long NW = (long)DM * DM / 4;    // 65536
    const long NS = GTOT / 4;             // 4096
    long i = (long)blockIdx.x * 256 + threadIdx.x;
    if (i < NK) {
        float4 f = ((const float4*)X)[i];
        ushort4 o;
        o.x = f2bf(f.x); o.y = f2bf(f.y); o.z = f2bf(f.z); o.w = f2bf(f.w);
        ((ushort4*)Kbf)[i] = o;
    } else if (i < NK + NW) {
        long j = i - NK;
        float4 f = ((const float4*)W)[j];
        ushort4 o;
        o.x = f2bf(f.x); o.y = f2bf(f.y); o.z = f2bf(f.z); o.w = f2bf(f.w);
        ((ushort4*)Wbf)[j] = o;
    } else if (i < NK + NW + NS) {
        ((float4*)ssbuf)[i - NK - NW] = (float4){0.f, 0.f, 0.f, 0.f};
    }
}

// ------------- kernel 1b: bit-pack mask, float4 loads + LDS nibble assembly -------------
__global__ __launch_bounds__(256) void k_maskpack(
    const float* __restrict__ mask, u64* __restrict__ Mbits) {
    __shared__ u8 nib[256];
    const int tid = threadIdx.x;
    const long fbase = (long)blockIdx.x * 256 + tid;  // float4 index
    float4 f = ((const float4*)mask)[fbase];
    unsigned n = (f.x != 0.f ? 1u : 0u) | (f.y != 0.f ? 2u : 0u) |
                 (f.z != 0.f ? 4u : 0u) | (f.w != 0.f ? 8u : 0u);
    nib[tid] = (u8)n;
    __syncthreads();
    if (tid < 16) {
        u64 w = 0;
#pragma unroll
        for (int i = 0; i < 16; ++i) w |= (u64)nib[tid * 16 + i] << (i * 4);
        Mbits[(long)blockIdx.x * 16 + tid] = w;
    }
}

// --- kernel 2: S = bitmask .* (X X^T) * INV_T (bf16) + row sum-of-squares ---
// 256x256 tile, BK=64, 512 thr / 8 waves (2x4), per-wave 128x64 (4x2 MFMA tiles).
// Deep-pipelined: counted vmcnt (A-half then B-half prefetch, 4..12 in flight),
// raw barriers, setprio'd 16-MFMA clusters. LDS 128 KiB dbuf. b = bid&7 -> XCD.
__global__ __launch_bounds__(512, 2) void k_sgemm(
    const u16* __restrict__ Kbf, const u32* __restrict__ Mw,
    u16* __restrict__ Sbuf, float* __restrict__ ssbuf) {
    __shared__ __attribute__((aligned(16))) u16 Sm[65536];  // 128 KiB
    u16* A0 = Sm;
    u16* B0 = Sm + 16384;
    u16* A1 = Sm + 32768;
    u16* B1 = Sm + 49152;

    const int tid = threadIdx.x, wave = tid >> 6, lane = tid & 63;
    const int l31 = lane & 31, lh = lane >> 5;
    const int wy = wave >> 2, wx = wave & 3;
    const int bid = blockIdx.x;
    const int b = bid & 7;                 // batch -> XCD affinity
    const int ty = (bid >> 3) & 7, tx = bid >> 6;
    const int M0 = ty * 256, N0 = tx * 256;
    const u16* Ag = Kbf + (long)(b * NSEQ + M0) * DM;
    const u16* Bg = Kbf + (long)(b * NSEQ + N0) * DM;
    const u32* Mb = Mw + (long)b * NSEQ * 64;  // 64 u32 words per row

    const int rS = wave * 32 + (lane >> 3);

    f32x16 acc[4][2];
#pragma unroll
    for (int i = 0; i < 4; ++i)
#pragma unroll
        for (int j = 0; j < 2; ++j)
#pragma unroll
            for (int e = 0; e < 16; ++e) acc[i][j][e] = 0.f;

    // prologue: tile 0 fully staged (8 loads/thread in flight)
    STG(Ag, DM, 0, A0);
    STG(Bg, DM, 0, B0);

#pragma unroll
    for (int t = 0; t < 8; ++t) {
        u16* Ac = (t & 1) ? A1 : A0;
        u16* Bc = (t & 1) ? B1 : B0;
        u16* An = (t & 1) ? A0 : A1;
        u16* Bn = (t & 1) ? B0 : B1;
        if (t < 7) {
            STG(Ag, DM, (t + 1) * 64, An);  // +4 -> 12 outstanding
            VMCNT(4);                       // tile t's 8 landed; next-A still flying
        } else {
            VMCNT(0);
        }
        BAR();
        QPHASE(Ac, Bc, 0);
        if (t < 7) STG(Bg, DM, (t + 1) * 64, Bn);  // back to 8 outstanding
        QPHASE(Ac, Bc, 2);
        BAR();  // all waves done reading buf t
    }

    // epilogue: bitmask multiply, bf16 nt-store, per-row sum-of-squares -> atomicAdd
#pragma unroll
    for (int rt = 0; rt < 4; ++rt) {
#pragma unroll
        for (int reg = 0; reg < 16; ++reg) {
            int rl = M0 + wy * 128 + rt * 32 + ROWOFF(reg, lh);
            long rg = (long)b * NSEQ + rl;
            float v = 0.f;
#pragma unroll
            for (int ct = 0; ct < 2; ++ct) {
                int cg = N0 + wx * 64 + ct * 32 + l31;
                u32 w = Mb[(long)rl * 64 + (cg >> 5)];
                float s = ((w >> l31) & 1u) ? acc[rt][ct][reg] * INV_T : 0.f;
                v += s * s;
                __builtin_nontemporal_store(f2bf(s), &Sbuf[rg * NSEQ + cg]);
            }
            v += __shfl_xor(v, 1, 32);
            v += __shfl_xor(v, 2, 32);
            v += __shfl_xor(v, 4, 32);
            v += __shfl_xor(v, 8, 32);
            v += __shfl_xor(v, 16, 32);
            if (l31 == 0) atomicAdd(&ssbuf[rg], v);
        }
    }
}

// ------------- kernel 3: vT[e][g] = elu(W X^T + b), 128x128 BK=64 -------------
__global__ __launch_bounds__(256, 4) void k_vgemm(
    const u16* __restrict__ Wbf, const u16* __restrict__ Kbf,
    const float* __restrict__ bias, u16* __restrict__ vT) {
    __shared__ __attribute__((aligned(16))) u16 Ab[8192], Bb[8192];
    const int tid = threadIdx.x, wave = tid >> 6, lane = tid & 63;
    const int l31 = lane & 31, lh = lane >> 5;
    const int wy = wave >> 1, wx = wave & 1;
    const int M0 = blockIdx.y * 128, N0 = blockIdx.x * 128;
    const u16* Ag = Wbf + (long)M0 * DM;
    const u16* Bg = Kbf + (long)N0 * DM;

    const int rS = wave * 32 + (lane >> 3);

    f32x16 acc[2][2];
#pragma unroll
    for (int i = 0; i < 2; ++i)
#pragma unroll
        for (int j = 0; j < 2; ++j)
#pragma unroll
            for (int e = 0; e < 16; ++e) acc[i][j][e] = 0.f;

    for (int kt = 0; kt < 8; ++kt) {
        const int k0 = kt * 64;
        __syncthreads();
        STAGE64(Ag, DM, Bg, DM, k0);
        __syncthreads();
#pragma unroll
        for (int ks = 0; ks < 4; ++ks) {
            const int kc = ks * 2 + lh;
            bf16x8 a0 = fragld64(Ab, wy * 64 + l31, kc);
            bf16x8 a1 = fragld64(Ab, wy * 64 + 32 + l31, kc);
            bf16x8 b0 = fragld64(Bb, wx * 64 + l31, kc);
            bf16x8 b1 = fragld64(Bb, wx * 64 + 32 + l31, kc);
            acc[0][0] = MFMA32(a0, b0, acc[0][0]);
            acc[0][1] = MFMA32(a0, b1, acc[0][1]);
            acc[1][0] = MFMA32(a1, b0, acc[1][0]);
            acc[1][1] = MFMA32(a1, b1, acc[1][1]);
        }
    }
#pragma unroll
    for (int mi = 0; mi < 2; ++mi) {
#pragma unroll
        for (int reg = 0; reg < 16; ++reg) {
            int e = M0 + wy * 64 + mi * 32 + ROWOFF(reg, lh);
            float bv = bias[e];
#pragma unroll
            for (int ni = 0; ni < 2; ++ni) {
                int g = N0 + wx * 64 + ni * 32 + l31;
                float x = acc[mi][ni][reg] + bv;
                float v = x > 0.f ? x : (__expf(x) - 1.f);
                vT[(long)e * GTOT + g] = f2bf(v);
            }
        }
    }
}

// -------- kernel 4: O = diag(1/max(||S_row||,eps)) * (S V), 128x128 BK=64 ------
__global__ __launch_bounds__(256, 4) void k_pv(
    const u16* __restrict__ Sbuf, const u16* __restrict__ vT,
    const float* __restrict__ ssbuf, float* __restrict__ Out) {
    __shared__ __attribute__((aligned(16))) u16 Ab[8192], Bb[8192];
    __shared__ float sc[128];
    const int tid = threadIdx.x, wave = tid >> 6, lane = tid & 63;
    const int l31 = lane & 31, lh = lane >> 5;
    const int wy = wave >> 1, wx = wave & 1;
    const int b = blockIdx.z;
    const int M0 = blockIdx.y * 128, N0 = blockIdx.x * 128;
    const u16* Ag = Sbuf + (long)(b * NSEQ + M0) * NSEQ;
    const u16* Bg = vT + (long)N0 * GTOT + b * NSEQ;

    if (tid < 128) {
        float v = ssbuf[b * NSEQ + M0 + tid];
        sc[tid] = 1.f / fmaxf(sqrtf(v), EPSN);
    }

    const int rS = wave * 32 + (lane >> 3);

    f32x16 acc[2][2];
#pragma unroll
    for (int i = 0; i < 2; ++i)
#pragma unroll
        for (int j = 0; j < 2; ++j)
#pragma unroll
            for (int e = 0; e < 16; ++e) acc[i][j][e] = 0.f;

    for (int kt = 0; kt < 32; ++kt) {
        const int k0 = kt * 64;
        __syncthreads();
        STAGE64(Ag, NSEQ, Bg, GTOT, k0);
        __syncthreads();
#pragma unroll
        for (int ks = 0; ks < 4; ++ks) {
            const int kc = ks * 2 + lh;
            bf16x8 a0 = fragld64(Ab, wy * 64 + l31, kc);
            bf16x8 a1 = fragld64(Ab, wy * 64 + 32 + l31, kc);
            bf16x8 b0 = fragld64(Bb, wx * 64 + l31, kc);
            bf16x8 b1 = fragld64(Bb, wx * 64 + 32 + l31, kc);
            acc[0][0] = MFMA32(a0, b0, acc[0][0]);
            acc[0][1] = MFMA32(a0, b1, acc[0][1]);
            acc[1][0] = MFMA32(a1, b0, acc[1][0]);
            acc[1][1] = MFMA32(a1, b1, acc[1][1]);
        }
    }
#pragma unroll
    for (int mi = 0; mi < 2; ++mi) {
#pragma unroll
        for (int reg = 0; reg < 16; ++reg) {
            int rl = wy * 64 + mi * 32 + ROWOFF(reg, lh);
            float s = sc[rl];
            float* op = Out + ((long)b * NSEQ + M0 + rl) * DM;
#pragma unroll
            for (int ni = 0; ni < 2; ++ni) {
                int d = N0 + wx * 64 + ni * 32 + l31;
                op[d] = acc[mi][ni][reg] * s;
            }
        }
    }
}

extern "C" void kernel_launch(void* const* d_in, const int* in_sizes, int n_in,
                              void* d_out, int out_size, void* d_ws, size_t ws_size,
                              hipStream_t stream) {
    const float* X = (const float*)d_in[0];
    const float* mask = (const float*)d_in[1];
    const float* W = (const float*)d_in[2];
    const float* bias = (const float*)d_in[3];
    float* out = (float*)d_out;

    char* ws = (char*)d_ws;
    u16* Kbf = (u16*)ws;                           // 16 MiB
    u16* Wbf = (u16*)(ws + 16777216);              // 512 KiB
    u16* vT = (u16*)(ws + 17301504);               // 16 MiB
    u16* Sbuf = (u16*)(ws + 34078720);             // 64 MiB
    float* ssbuf = (float*)(ws + 101187584);       // 64 KiB
    u64* Mbits = (u64*)(ws + 101253120);           // 4 MiB (packed mask)

    k_convert<<<8464, 256, 0, stream>>>(X, W, Kbf, Wbf, ssbuf);
    k_maskpack<<<32768, 256, 0, stream>>>(mask, Mbits);
    k_vgemm<<<dim3(128, 4), 256, 0, stream>>>(Wbf, Kbf, bias, vT);
    k_sgemm<<<512, 512, 0, stream>>>(Kbf, (const u32*)Mbits, Sbuf, ssbuf);
    k_pv<<<dim3(4, 16, 8), 256, 0, stream>>>(Sbuf, vT, ssbuf, out);
}

// Round 3
// 333.605 us; speedup vs baseline: 1.1872x; 1.1727x over previous
//
#include <hip/hip_runtime.h>
#include <hip/hip_bf16.h>

#define NSEQ 2048
#define DM 512
#define BATCH 8
#define GTOT (BATCH * NSEQ)          // 16384
#define INV_T 0.044194173824159216f  // 1/sqrt(512)
#define EPSN 1e-5f

typedef __bf16 bf16_t;
typedef bf16_t bf16x8 __attribute__((ext_vector_type(8)));
typedef float f32x16 __attribute__((ext_vector_type(16)));
typedef unsigned short u16;
typedef unsigned int u32;
typedef unsigned long long u64;

__device__ __forceinline__ u16 f2bf(float f) {
    u32 u = __builtin_bit_cast(u32, f);
    u32 r = (u + 0x7FFFu + ((u >> 16) & 1u)) >> 16;
    return (u16)r;
}

// async global->LDS DMA, 16 B per lane. LDS dest = wave-uniform base + lane*16 B.
__device__ __forceinline__ void async16(const u16* g, u16* l) {
    __builtin_amdgcn_global_load_lds(
        (const __attribute__((address_space(1))) u32*)g,
        (__attribute__((address_space(3))) u32*)l, 16, 0, 0);
}

// BK=64 LDS tile: rows x 64 k-elems (128 B rows), 8 16-B chunks XOR-swizzled by ((row>>1)&7).
__device__ __forceinline__ bf16x8 fragld64(const u16* t, int row, int kc) {
    return *(const bf16x8*)(t + row * 64 + ((kc ^ ((row >> 1) & 7)) << 3));
}

#define MFMA32(a, b, c) __builtin_amdgcn_mfma_f32_32x32x16_bf16(a, b, c, 0, 0, 0)
#define ROWOFF(reg, lh) (((reg) & 3) + 8 * ((reg) >> 2) + 4 * (lh))

// BK=64 staging: 8 issues/thread (4 A + 4 B). Issue u = wave*4+j covers LDS rows
// u*8..u*8+7; lane supplies row u*8+(lane>>3), chunk (lane&7), fetching the
// global chunk that fragld64's XOR expects at that slot.
#define STAGE64(Ag, ldA, Bg, ldB, k0)                                            \
    do {                                                                         \
        _Pragma("unroll") for (int j = 0; j < 4; ++j) {                          \
            const int cg = (lane & 7) ^ ((j * 4 + (lane >> 4)) & 7);             \
            const int dst = (wave * 4 + j) * 512 + lane * 8;                     \
            async16((Ag) + (long)(rS + j * 8) * (ldA) + (k0) + cg * 8, Ab + dst);\
            async16((Bg) + (long)(rS + j * 8) * (ldB) + (k0) + cg * 8, Bb + dst);\
        }                                                                        \
    } while (0)

// ---------------- kernel 1: f32 -> bf16 of X and W; zero ssbuf ----------------
__global__ __launch_bounds__(256) void k_convert(
    const float* __restrict__ X, const float* __restrict__ W,
    u16* __restrict__ Kbf, u16* __restrict__ Wbf, float* __restrict__ ssbuf) {
    const long NK = (long)GTOT * DM / 4;  // 2097152
    const long NW = (long)DM * DM / 4;    // 65536
    const long NS = GTOT / 4;             // 4096
    long i = (long)blockIdx.x * 256 + threadIdx.x;
    if (i < NK) {
        float4 f = ((const float4*)X)[i];
        ushort4 o;
        o.x = f2bf(f.x); o.y = f2bf(f.y); o.z = f2bf(f.z); o.w = f2bf(f.w);
        ((ushort4*)Kbf)[i] = o;
    } else if (i < NK + NW) {
        long j = i - NK;
        float4 f = ((const float4*)W)[j];
        ushort4 o;
        o.x = f2bf(f.x); o.y = f2bf(f.y); o.z = f2bf(f.z); o.w = f2bf(f.w);
        ((ushort4*)Wbf)[j] = o;
    } else if (i < NK + NW + NS) {
        ((float4*)ssbuf)[i - NK - NW] = (float4){0.f, 0.f, 0.f, 0.f};
    }
}

// --- kernel 2: S = mask .* (X X^T) * INV_T (bf16) + row sum-of-squares ---
// 128x128 tile, BK=64, 256 thr, 4 waves (2x2), wave tile 64x64.
// 1-D grid, b = bid&7 -> XCD affinity (per-XCD working set = one batch's K panels).
// Mask read fused: f32 mask consumed exactly once, in the epilogue.
__global__ __launch_bounds__(256, 4) void k_sgemm(
    const u16* __restrict__ Kbf, const float* __restrict__ mask,
    u16* __restrict__ Sbuf, float* __restrict__ ssbuf) {
    __shared__ __attribute__((aligned(16))) u16 Ab[8192], Bb[8192];
    const int tid = threadIdx.x, wave = tid >> 6, lane = tid & 63;
    const int l31 = lane & 31, lh = lane >> 5;
    const int wy = wave >> 1, wx = wave & 1;
    const int bid = blockIdx.x;
    const int b = bid & 7;                       // batch -> XCD
    const int ty = (bid >> 3) & 15, tx = bid >> 7;
    const int M0 = ty * 128, N0 = tx * 128;
    const u16* Ag = Kbf + (long)(b * NSEQ + M0) * DM;
    const u16* Bg = Kbf + (long)(b * NSEQ + N0) * DM;

    const int rS = wave * 32 + (lane >> 3);

    f32x16 acc[2][2];
#pragma unroll
    for (int i = 0; i < 2; ++i)
#pragma unroll
        for (int j = 0; j < 2; ++j)
#pragma unroll
            for (int e = 0; e < 16; ++e) acc[i][j][e] = 0.f;

    for (int kt = 0; kt < 8; ++kt) {
        const int k0 = kt * 64;
        __syncthreads();
        STAGE64(Ag, DM, Bg, DM, k0);
        __syncthreads();
#pragma unroll
        for (int ks = 0; ks < 4; ++ks) {
            const int kc = ks * 2 + lh;
            bf16x8 a0 = fragld64(Ab, wy * 64 + l31, kc);
            bf16x8 a1 = fragld64(Ab, wy * 64 + 32 + l31, kc);
            bf16x8 b0 = fragld64(Bb, wx * 64 + l31, kc);
            bf16x8 b1 = fragld64(Bb, wx * 64 + 32 + l31, kc);
            acc[0][0] = MFMA32(a0, b0, acc[0][0]);
            acc[0][1] = MFMA32(a0, b1, acc[0][1]);
            acc[1][0] = MFMA32(a1, b0, acc[1][0]);
            acc[1][1] = MFMA32(a1, b1, acc[1][1]);
        }
    }
    // epilogue: f32 mask multiply, bf16 store (L3-cached for k_pv), row sum-of-squares
#pragma unroll
    for (int mi = 0; mi < 2; ++mi) {
#pragma unroll
        for (int reg = 0; reg < 16; ++reg) {
            int rl = M0 + wy * 64 + mi * 32 + ROWOFF(reg, lh);
            long rg = (long)b * NSEQ + rl;
            const float* mrow = mask + rg * NSEQ;
            float v = 0.f;
#pragma unroll
            for (int ni = 0; ni < 2; ++ni) {
                int cg = N0 + wx * 64 + ni * 32 + l31;
                float s = acc[mi][ni][reg] * INV_T * mrow[cg];
                v += s * s;
                Sbuf[rg * NSEQ + cg] = f2bf(s);
            }
            v += __shfl_xor(v, 1, 32);
            v += __shfl_xor(v, 2, 32);
            v += __shfl_xor(v, 4, 32);
            v += __shfl_xor(v, 8, 32);
            v += __shfl_xor(v, 16, 32);
            if (l31 == 0) atomicAdd(&ssbuf[rg], v);
        }
    }
}

// ------------- kernel 3: vT[e][g] = elu(W X^T + b), 128x128 BK=64 -------------
__global__ __launch_bounds__(256, 4) void k_vgemm(
    const u16* __restrict__ Wbf, const u16* __restrict__ Kbf,
    const float* __restrict__ bias, u16* __restrict__ vT) {
    __shared__ __attribute__((aligned(16))) u16 Ab[8192], Bb[8192];
    const int tid = threadIdx.x, wave = tid >> 6, lane = tid & 63;
    const int l31 = lane & 31, lh = lane >> 5;
    const int wy = wave >> 1, wx = wave & 1;
    const int M0 = blockIdx.y * 128, N0 = blockIdx.x * 128;
    const u16* Ag = Wbf + (long)M0 * DM;
    const u16* Bg = Kbf + (long)N0 * DM;

    const int rS = wave * 32 + (lane >> 3);

    f32x16 acc[2][2];
#pragma unroll
    for (int i = 0; i < 2; ++i)
#pragma unroll
        for (int j = 0; j < 2; ++j)
#pragma unroll
            for (int e = 0; e < 16; ++e) acc[i][j][e] = 0.f;

    for (int kt = 0; kt < 8; ++kt) {
        const int k0 = kt * 64;
        __syncthreads();
        STAGE64(Ag, DM, Bg, DM, k0);
        __syncthreads();
#pragma unroll
        for (int ks = 0; ks < 4; ++ks) {
            const int kc = ks * 2 + lh;
            bf16x8 a0 = fragld64(Ab, wy * 64 + l31, kc);
            bf16x8 a1 = fragld64(Ab, wy * 64 + 32 + l31, kc);
            bf16x8 b0 = fragld64(Bb, wx * 64 + l31, kc);
            bf16x8 b1 = fragld64(Bb, wx * 64 + 32 + l31, kc);
            acc[0][0] = MFMA32(a0, b0, acc[0][0]);
            acc[0][1] = MFMA32(a0, b1, acc[0][1]);
            acc[1][0] = MFMA32(a1, b0, acc[1][0]);
            acc[1][1] = MFMA32(a1, b1, acc[1][1]);
        }
    }
#pragma unroll
    for (int mi = 0; mi < 2; ++mi) {
#pragma unroll
        for (int reg = 0; reg < 16; ++reg) {
            int e = M0 + wy * 64 + mi * 32 + ROWOFF(reg, lh);
            float bv = bias[e];
#pragma unroll
            for (int ni = 0; ni < 2; ++ni) {
                int g = N0 + wx * 64 + ni * 32 + l31;
                float x = acc[mi][ni][reg] + bv;
                float v = x > 0.f ? x : (__expf(x) - 1.f);
                vT[(long)e * GTOT + g] = f2bf(v);
            }
        }
    }
}

// -------- kernel 4: O = diag(1/max(||S_row||,eps)) * (S V), 128x128 BK=64 ------
// 1-D grid, b = bid&7 -> XCD affinity (vT batch slice 2 MiB + S panels stay in L2).
__global__ __launch_bounds__(256, 4) void k_pv(
    const u16* __restrict__ Sbuf, const u16* __restrict__ vT,
    const float* __restrict__ ssbuf, float* __restrict__ Out) {
    __shared__ __attribute__((aligned(16))) u16 Ab[8192], Bb[8192];
    __shared__ float sc[128];
    const int tid = threadIdx.x, wave = tid >> 6, lane = tid & 63;
    const int l31 = lane & 31, lh = lane >> 5;
    const int wy = wave >> 1, wx = wave & 1;
    const int bid = blockIdx.x;
    const int b = bid & 7;                       // batch -> XCD
    const int r = bid >> 3;
    const int tx = r & 3, ty = r >> 2;
    const int M0 = ty * 128, N0 = tx * 128;
    const u16* Ag = Sbuf + (long)(b * NSEQ + M0) * NSEQ;
    const u16* Bg = vT + (long)N0 * GTOT + b * NSEQ;

    if (tid < 128) {
        float v = ssbuf[b * NSEQ + M0 + tid];
        sc[tid] = 1.f / fmaxf(sqrtf(v), EPSN);
    }

    const int rS = wave * 32 + (lane >> 3);

    f32x16 acc[2][2];
#pragma unroll
    for (int i = 0; i < 2; ++i)
#pragma unroll
        for (int j = 0; j < 2; ++j)
#pragma unroll
            for (int e = 0; e < 16; ++e) acc[i][j][e] = 0.f;

    for (int kt = 0; kt < 32; ++kt) {
        const int k0 = kt * 64;
        __syncthreads();
        STAGE64(Ag, NSEQ, Bg, GTOT, k0);
        __syncthreads();
#pragma unroll
        for (int ks = 0; ks < 4; ++ks) {
            const int kc = ks * 2 + lh;
            bf16x8 a0 = fragld64(Ab, wy * 64 + l31, kc);
            bf16x8 a1 = fragld64(Ab, wy * 64 + 32 + l31, kc);
            bf16x8 b0 = fragld64(Bb, wx * 64 + l31, kc);
            bf16x8 b1 = fragld64(Bb, wx * 64 + 32 + l31, kc);
            acc[0][0] = MFMA32(a0, b0, acc[0][0]);
            acc[0][1] = MFMA32(a0, b1, acc[0][1]);
            acc[1][0] = MFMA32(a1, b0, acc[1][0]);
            acc[1][1] = MFMA32(a1, b1, acc[1][1]);
        }
    }
#pragma unroll
    for (int mi = 0; mi < 2; ++mi) {
#pragma unroll
        for (int reg = 0; reg < 16; ++reg) {
            int rl = wy * 64 + mi * 32 + ROWOFF(reg, lh);
            float s = sc[rl];
            float* op = Out + ((long)b * NSEQ + M0 + rl) * DM;
#pragma unroll
            for (int ni = 0; ni < 2; ++ni) {
                int d = N0 + wx * 64 + ni * 32 + l31;
                op[d] = acc[mi][ni][reg] * s;
            }
        }
    }
}

extern "C" void kernel_launch(void* const* d_in, const int* in_sizes, int n_in,
                              void* d_out, int out_size, void* d_ws, size_t ws_size,
                              hipStream_t stream) {
    const float* X = (const float*)d_in[0];
    const float* mask = (const float*)d_in[1];
    const float* W = (const float*)d_in[2];
    const float* bias = (const float*)d_in[3];
    float* out = (float*)d_out;

    char* ws = (char*)d_ws;
    u16* Kbf = (u16*)ws;                           // 16 MiB
    u16* Wbf = (u16*)(ws + 16777216);              // 512 KiB
    u16* vT = (u16*)(ws + 17301504);               // 16 MiB
    u16* Sbuf = (u16*)(ws + 34078720);             // 64 MiB
    float* ssbuf = (float*)(ws + 101187584);       // 64 KiB

    k_convert<<<8464, 256, 0, stream>>>(X, W, Kbf, Wbf, ssbuf);
    k_vgemm<<<dim3(128, 4), 256, 0, stream>>>(Wbf, Kbf, bias, vT);
    k_sgemm<<<2048, 256, 0, stream>>>(Kbf, mask, Sbuf, ssbuf);
    k_pv<<<512, 256, 0, stream>>>(Sbuf, vT, ssbuf, out);
}